// Round 1
// baseline (1654.736 us; speedup 1.0000x reference)
//
#include <hip/hip_runtime.h>
#include <math.h>

// Problem constants
#define BB_ 8
#define C_ 512
#define C3_ 1536
#define HW_ 1024
#define NH_ 8
#define DH_ 64
#define HH_ 32
#define WW_ 32

// -------------------------------------------------------------------------
// K1: t[b,n,c] = x[b,c,n] + pos[n,c]   (token-major output)
__global__ void add_pos_kernel(const float* __restrict__ x,
                               const float* __restrict__ pos,
                               float* __restrict__ t) {
  int idx = blockIdx.x * 256 + threadIdx.x;       // over B*HW*C = 4M
  int c = idx & (C_ - 1);
  int bn = idx >> 9;                               // b*HW + n
  int n = bn & (HW_ - 1);
  int b = bn >> 10;
  t[idx] = x[((size_t)(b * C_ + c)) * HW_ + n] + pos[n * C_ + c];
}

// -------------------------------------------------------------------------
// Generic GEMM: out[m,j] = sum_k A[m,k] * W[j,k] (+bias[j])
// A row-major [M,K], W row-major [N,K]. M fixed 8192-multiple-of-64 tiles.
// EPI==0: store token-major [m*N+j].
// EPI==1: store NCHW out[(b*C + j)*HW + s] = acc + bias[j] + resid[m*C + j]
template <int EPI>
__global__ __launch_bounds__(256) void gemm_nt(
    const float* __restrict__ A, const float* __restrict__ W,
    const float* __restrict__ bias, float* __restrict__ out,
    const float* __restrict__ resid, int N, int K) {
  __shared__ float As[16][65];
  __shared__ float Ws[16][65];
  const int bn = blockIdx.x * 64, bm = blockIdx.y * 64;
  const int tid = threadIdx.x;
  const int tx = tid & 15, ty = tid >> 4;
  float acc[4][4] = {};
  for (int k0 = 0; k0 < K; k0 += 16) {
#pragma unroll
    for (int l = tid; l < 1024; l += 256) {
      int m = l >> 4, kk = l & 15;
      As[kk][m] = A[(size_t)(bm + m) * K + k0 + kk];
      Ws[kk][m] = W[(size_t)(bn + m) * K + k0 + kk];
    }
    __syncthreads();
#pragma unroll
    for (int kk = 0; kk < 16; kk++) {
      float a[4], w[4];
#pragma unroll
      for (int i = 0; i < 4; i++) a[i] = As[kk][ty * 4 + i];
#pragma unroll
      for (int j = 0; j < 4; j++) w[j] = Ws[kk][tx * 4 + j];
#pragma unroll
      for (int i = 0; i < 4; i++)
#pragma unroll
        for (int j = 0; j < 4; j++) acc[i][j] += a[i] * w[j];
    }
    __syncthreads();
  }
  if (EPI == 0) {
#pragma unroll
    for (int i = 0; i < 4; i++) {
      int m = bm + ty * 4 + i;
#pragma unroll
      for (int j = 0; j < 4; j++) {
        int jj = bn + tx * 4 + j;
        float v = acc[i][j] + (bias ? bias[jj] : 0.0f);
        out[(size_t)m * N + jj] = v;
      }
    }
  } else {
#pragma unroll
    for (int j = 0; j < 4; j++) {
      int jj = bn + tx * 4 + j;
      float bv = bias[jj];
#pragma unroll
      for (int i = 0; i < 4; i++) {
        int m = bm + ty * 4 + i;
        int b = m >> 10, s = m & (HW_ - 1);
        out[((size_t)(b * C_ + jj)) * HW_ + s] =
            acc[i][j] + bv + resid[(size_t)m * C_ + jj];
      }
    }
  }
}

// -------------------------------------------------------------------------
// K3: per (b,h,d) token-axis L2 norms of q and k -> reciprocal
__global__ void qk_norms_kernel(const float* __restrict__ qkv,
                                float* __restrict__ invq,
                                float* __restrict__ invk) {
  int bh = blockIdx.x;                 // b*NH + h
  int b = bh >> 3, h = bh & 7;
  int d = threadIdx.x & 63, g = threadIdx.x >> 6;
  float sq = 0.f, sk = 0.f;
  const float* base = qkv + (size_t)b * HW_ * C3_ + h * 64 + d;
  for (int n = g; n < HW_; n += 4) {
    float qv = base[(size_t)n * C3_];
    float kv = base[(size_t)n * C3_ + C_];
    sq += qv * qv;
    sk += kv * kv;
  }
  __shared__ float smq[4][64], smk[4][64];
  smq[g][d] = sq;
  smk[g][d] = sk;
  __syncthreads();
  if (threadIdx.x < 64) {
    float q2 = smq[0][d] + smq[1][d] + smq[2][d] + smq[3][d];
    float k2 = smk[0][d] + smk[1][d] + smk[2][d] + smk[3][d];
    invq[bh * 64 + d] = 1.0f / fmaxf(sqrtf(q2), 1e-12f);
    invk[bh * 64 + d] = 1.0f / fmaxf(sqrtf(k2), 1e-12f);
  }
}

// -------------------------------------------------------------------------
// K4: attention for a tile of 4 queries per block. Two-pass softmax with
// scores kept in LDS; K/V tiles (64 x 64) staged through LDS.
__global__ __launch_bounds__(256) void attn_kernel(
    const float* __restrict__ qkv, const float* __restrict__ invq,
    const float* __restrict__ invk, const float* __restrict__ temp,
    float* __restrict__ o) {
  __shared__ float qk[4][64];
  __shared__ float sc[4][HW_];
  __shared__ float tile[64][65];
  __shared__ float red2[4][4][64];
  __shared__ float winv[4];
  const int t = threadIdx.x;
  const int nt = blockIdx.x & 255;
  const int bh = blockIdx.x >> 8;       // b*NH + h
  const int b = bh >> 3, h = bh & 7;
  const int n0 = nt * 4;
  {
    int qi = t >> 6, d = t & 63;
    // fold invq (this query col), invk (key col, d-only) and temperature
    qk[qi][d] = qkv[((size_t)(b * HW_ + n0 + qi)) * C3_ + h * 64 + d] *
                invq[bh * 64 + d] * invk[bh * 64 + d] * temp[h];
  }
  const float* kbase = qkv + (size_t)b * HW_ * C3_ + C_ + h * 64;
  const float* vbase = qkv + (size_t)b * HW_ * C3_ + 2 * C_ + h * 64;
  __syncthreads();
  // ---- pass 1: scores
  const int ml = t >> 2, part = t & 3;
  for (int mt = 0; mt < HW_; mt += 64) {
    for (int l = t; l < 4096; l += 256)
      tile[l >> 6][l & 63] = kbase[(size_t)(mt + (l >> 6)) * C3_ + (l & 63)];
    __syncthreads();
    float s0 = 0, s1 = 0, s2 = 0, s3 = 0;
#pragma unroll
    for (int i = 0; i < 16; i++) {
      float kv = tile[ml][part * 16 + i];
      s0 += qk[0][part * 16 + i] * kv;
      s1 += qk[1][part * 16 + i] * kv;
      s2 += qk[2][part * 16 + i] * kv;
      s3 += qk[3][part * 16 + i] * kv;
    }
    s0 += __shfl_xor(s0, 1); s0 += __shfl_xor(s0, 2);
    s1 += __shfl_xor(s1, 1); s1 += __shfl_xor(s1, 2);
    s2 += __shfl_xor(s2, 1); s2 += __shfl_xor(s2, 2);
    s3 += __shfl_xor(s3, 1); s3 += __shfl_xor(s3, 2);
    if (part == 0) {
      sc[0][mt + ml] = s0;
      sc[1][mt + ml] = s1;
      sc[2][mt + ml] = s2;
      sc[3][mt + ml] = s3;
    }
    __syncthreads();
  }
  // ---- softmax: wave wv owns query wv
  {
    int wv = t >> 6, ln = t & 63;
    float lm = -1e30f;
    for (int m = ln; m < HW_; m += 64) lm = fmaxf(lm, sc[wv][m]);
#pragma unroll
    for (int off = 32; off; off >>= 1) lm = fmaxf(lm, __shfl_xor(lm, off));
    float ls = 0;
    for (int m = ln; m < HW_; m += 64) {
      float e = __expf(sc[wv][m] - lm);
      sc[wv][m] = e;
      ls += e;
    }
#pragma unroll
    for (int off = 32; off; off >>= 1) ls += __shfl_xor(ls, off);
    if (ln == 0) winv[wv] = 1.0f / ls;
  }
  __syncthreads();
  // ---- pass 2: PV
  const int d = t & 63, mg = t >> 6;
  float a0 = 0, a1 = 0, a2 = 0, a3 = 0;
  for (int mt = 0; mt < HW_; mt += 64) {
    for (int l = t; l < 4096; l += 256)
      tile[l >> 6][l & 63] = vbase[(size_t)(mt + (l >> 6)) * C3_ + (l & 63)];
    __syncthreads();
#pragma unroll
    for (int i = 0; i < 16; i++) {
      float vv = tile[mg * 16 + i][d];
      int m = mt + mg * 16 + i;
      a0 += sc[0][m] * vv;
      a1 += sc[1][m] * vv;
      a2 += sc[2][m] * vv;
      a3 += sc[3][m] * vv;
    }
    __syncthreads();
  }
  red2[0][mg][d] = a0;
  red2[1][mg][d] = a1;
  red2[2][mg][d] = a2;
  red2[3][mg][d] = a3;
  __syncthreads();
  {
    int qi = t >> 6, dd = t & 63;
    float r = red2[qi][0][dd] + red2[qi][1][dd] + red2[qi][2][dd] +
              red2[qi][3][dd];
    o[((size_t)(b * HW_ + n0 + qi)) * C_ + h * 64 + dd] = r * winv[qi];
  }
}

// -------------------------------------------------------------------------
// K6: LayerNorm over C per token + residual add of x (NCHW), output token-major
__global__ void ln_residual_kernel(const float* __restrict__ po,
                                   const float* __restrict__ x,
                                   const float* __restrict__ g,
                                   const float* __restrict__ bb,
                                   float* __restrict__ y) {
  int token = blockIdx.x;  // b*HW + n
  int b = token >> 10, n = token & (HW_ - 1);
  int t = threadIdx.x;
  const float* row = po + (size_t)token * C_;
  float v0 = row[t], v1 = row[t + 256];
  float s = v0 + v1;
#pragma unroll
  for (int off = 32; off; off >>= 1) s += __shfl_xor(s, off);
  __shared__ float wr[4];
  if ((t & 63) == 0) wr[t >> 6] = s;
  __syncthreads();
  float mu = (wr[0] + wr[1] + wr[2] + wr[3]) * (1.0f / C_);
  float d0 = v0 - mu, d1 = v1 - mu;
  float vs = d0 * d0 + d1 * d1;
#pragma unroll
  for (int off = 32; off; off >>= 1) vs += __shfl_xor(vs, off);
  __syncthreads();
  if ((t & 63) == 0) wr[t >> 6] = vs;
  __syncthreads();
  float var = (wr[0] + wr[1] + wr[2] + wr[3]) * (1.0f / C_);
  float rstd = rsqrtf(var + 1e-5f);
  float o0 = d0 * rstd * g[t] + bb[t] + x[((size_t)(b * C_ + t)) * HW_ + n];
  float o1 = d1 * rstd * g[t + 256] + bb[t + 256] +
             x[((size_t)(b * C_ + t + 256)) * HW_ + n];
  y[(size_t)token * C_ + t] = o0;
  y[(size_t)token * C_ + t + 256] = o1;
}

// -------------------------------------------------------------------------
// K7: depthwise 3x3 SAME on token-major y -> token-major out (+dw bias)
__global__ void dwconv_kernel(const float* __restrict__ y,
                              const float* __restrict__ w,
                              const float* __restrict__ bias,
                              float* __restrict__ out) {
  int token = blockIdx.x;  // b*HW + s
  int b = token >> 10, s = token & (HW_ - 1);
  int hh = s >> 5, ww = s & 31;
  int t = threadIdx.x;
  for (int c = t; c < C_; c += 256) {
    float acc = bias[c];
#pragma unroll
    for (int ky = 0; ky < 3; ky++) {
      int yy = hh + ky - 1;
      if (yy < 0 || yy >= HH_) continue;
#pragma unroll
      for (int kx = 0; kx < 3; kx++) {
        int xx = ww + kx - 1;
        if (xx < 0 || xx >= WW_) continue;
        acc += w[c * 9 + ky * 3 + kx] *
               y[((size_t)(b * HW_ + yy * 32 + xx)) * C_ + c];
      }
    }
    out[(size_t)token * C_ + c] = acc;
  }
}

// -------------------------------------------------------------------------
extern "C" void kernel_launch(void* const* d_in, const int* in_sizes, int n_in,
                              void* d_out, int out_size, void* d_ws,
                              size_t ws_size, hipStream_t stream) {
  const float* x = (const float*)d_in[0];
  const float* qkv_w = (const float*)d_in[1];
  const float* proj_w = (const float*)d_in[2];
  const float* proj_b = (const float*)d_in[3];
  const float* temperature = (const float*)d_in[4];
  const float* ln_g = (const float*)d_in[5];
  const float* ln_b = (const float*)d_in[6];
  const float* pos = (const float*)d_in[7];
  const float* dw_w = (const float*)d_in[8];
  const float* dw_b = (const float*)d_in[9];
  const float* pw_w = (const float*)d_in[10];
  const float* pw_b = (const float*)d_in[11];
  float* out = (float*)d_out;

  float* ws = (float*)d_ws;
  // Region A: 12M floats — qkv, later first 4M reused for proj-out, then dwconv-out
  // Region B: 4M floats  — t, later attn-out, later y (post-LN residual)
  float* bufA = ws;
  float* bufB = ws + (size_t)12 * 1024 * 1024;
  float* invq = bufB + (size_t)4 * 1024 * 1024;
  float* invk = invq + BB_ * NH_ * DH_;

  const int M = BB_ * HW_;  // 8192 tokens

  // 1) t = transpose(x) + pos_embed              -> bufB
  add_pos_kernel<<<M * C_ / 256, 256, 0, stream>>>(x, pos, bufB);
  // 2) qkv = t @ qkv_w^T                          -> bufA [8192,1536]
  gemm_nt<0><<<dim3(C3_ / 64, M / 64), 256, 0, stream>>>(
      bufB, qkv_w, nullptr, bufA, nullptr, C3_, C_);
  // 3) token-axis L2 norms of q,k
  qk_norms_kernel<<<BB_ * NH_, 256, 0, stream>>>(bufA, invq, invk);
  // 4) attention                                  -> bufB [8192,512]
  attn_kernel<<<BB_ * NH_ * HW_ / 4, 256, 0, stream>>>(bufA, invq, invk,
                                                       temperature, bufB);
  // 5) proj: o @ proj_w^T + proj_b                -> bufA[0..4M)
  gemm_nt<0><<<dim3(C_ / 64, M / 64), 256, 0, stream>>>(
      bufB, proj_w, proj_b, bufA, nullptr, C_, C_);
  // 6) LayerNorm + residual(x)                    -> bufB (token-major y)
  ln_residual_kernel<<<M, 256, 0, stream>>>(bufA, x, ln_g, ln_b, bufB);
  // 7) depthwise 3x3 + dw_b                       -> bufA[0..4M)
  dwconv_kernel<<<M, 256, 0, stream>>>(bufB, dw_w, dw_b, bufA);
  // 8) pointwise 1x1 + pw_b + residual(y), NCHW   -> d_out
  gemm_nt<1><<<dim3(C_ / 64, M / 64), 256, 0, stream>>>(
      bufA, pw_w, pw_b, out, bufB, C_, C_);
}

// Round 2
// 800.884 us; speedup vs baseline: 2.0661x; 2.0661x over previous
//
#include <hip/hip_runtime.h>
#include <math.h>

// Problem constants
#define BB_ 8
#define C_ 512
#define C3_ 1536
#define HW_ 1024
#define NH_ 8
#define DH_ 64
#define HH_ 32
#define WW_ 32

typedef __attribute__((ext_vector_type(8))) short short8;
typedef __attribute__((ext_vector_type(4))) float f32x4;

__device__ inline unsigned short f2bf(float f) {
  union { float f; unsigned u; } v;
  v.f = f;
  unsigned r = v.u + 0x7fffu + ((v.u >> 16) & 1u);
  return (unsigned short)(r >> 16);
}

// -------------------------------------------------------------------------
// K1: t[b,n,c] = x[b,c,n] + pos[n,c]   (token-major output)
__global__ void add_pos_kernel(const float* __restrict__ x,
                               const float* __restrict__ pos,
                               float* __restrict__ t) {
  int idx = blockIdx.x * 256 + threadIdx.x;       // over B*HW*C = 4M
  int c = idx & (C_ - 1);
  int bn = idx >> 9;                               // b*HW + n
  int n = bn & (HW_ - 1);
  int b = bn >> 10;
  t[idx] = x[((size_t)(b * C_ + c)) * HW_ + n] + pos[n * C_ + c];
}

// -------------------------------------------------------------------------
// Generic GEMM: out[m,j] = sum_k A[m,k] * W[j,k] (+bias[j])
template <int EPI>
__global__ __launch_bounds__(256) void gemm_nt(
    const float* __restrict__ A, const float* __restrict__ W,
    const float* __restrict__ bias, float* __restrict__ out,
    const float* __restrict__ resid, int N, int K) {
  __shared__ float As[16][65];
  __shared__ float Ws[16][65];
  const int bn = blockIdx.x * 64, bm = blockIdx.y * 64;
  const int tid = threadIdx.x;
  const int tx = tid & 15, ty = tid >> 4;
  float acc[4][4] = {};
  for (int k0 = 0; k0 < K; k0 += 16) {
#pragma unroll
    for (int l = tid; l < 1024; l += 256) {
      int m = l >> 4, kk = l & 15;
      As[kk][m] = A[(size_t)(bm + m) * K + k0 + kk];
      Ws[kk][m] = W[(size_t)(bn + m) * K + k0 + kk];
    }
    __syncthreads();
#pragma unroll
    for (int kk = 0; kk < 16; kk++) {
      float a[4], w[4];
#pragma unroll
      for (int i = 0; i < 4; i++) a[i] = As[kk][ty * 4 + i];
#pragma unroll
      for (int j = 0; j < 4; j++) w[j] = Ws[kk][tx * 4 + j];
#pragma unroll
      for (int i = 0; i < 4; i++)
#pragma unroll
        for (int j = 0; j < 4; j++) acc[i][j] += a[i] * w[j];
    }
    __syncthreads();
  }
  if (EPI == 0) {
#pragma unroll
    for (int i = 0; i < 4; i++) {
      int m = bm + ty * 4 + i;
#pragma unroll
      for (int j = 0; j < 4; j++) {
        int jj = bn + tx * 4 + j;
        float v = acc[i][j] + (bias ? bias[jj] : 0.0f);
        out[(size_t)m * N + jj] = v;
      }
    }
  } else {
#pragma unroll
    for (int j = 0; j < 4; j++) {
      int jj = bn + tx * 4 + j;
      float bv = bias[jj];
#pragma unroll
      for (int i = 0; i < 4; i++) {
        int m = bm + ty * 4 + i;
        int b = m >> 10, s = m & (HW_ - 1);
        out[((size_t)(b * C_ + jj)) * HW_ + s] =
            acc[i][j] + bv + resid[(size_t)m * C_ + jj];
      }
    }
  }
}

// -------------------------------------------------------------------------
// K3: per (b,h,d) token-axis L2 norms of q and k -> reciprocal
__global__ void qk_norms_kernel(const float* __restrict__ qkv,
                                float* __restrict__ invq,
                                float* __restrict__ invk) {
  int bh = blockIdx.x;                 // b*NH + h
  int b = bh >> 3, h = bh & 7;
  int d = threadIdx.x & 63, g = threadIdx.x >> 6;
  float sq = 0.f, sk = 0.f;
  const float* base = qkv + (size_t)b * HW_ * C3_ + h * 64 + d;
  for (int n = g; n < HW_; n += 4) {
    float qv = base[(size_t)n * C3_];
    float kv = base[(size_t)n * C3_ + C_];
    sq += qv * qv;
    sk += kv * kv;
  }
  __shared__ float smq[4][64], smk[4][64];
  smq[g][d] = sq;
  smk[g][d] = sk;
  __syncthreads();
  if (threadIdx.x < 64) {
    float q2 = smq[0][d] + smq[1][d] + smq[2][d] + smq[3][d];
    float k2 = smk[0][d] + smk[1][d] + smk[2][d] + smk[3][d];
    invq[bh * 64 + d] = 1.0f / fmaxf(sqrtf(q2), 1e-12f);
    invk[bh * 64 + d] = 1.0f / fmaxf(sqrtf(k2), 1e-12f);
  }
}

// -------------------------------------------------------------------------
// K4: MFMA flash attention. Block = 4 waves = one 64-query tile of one
// (b,h). Online softmax over 16 K/V-tiles of 64. K/V staged bf16 in LDS
// (V transposed); P round-trips through LDS (C-layout -> A-layout).
__global__ __launch_bounds__(256) void attn_mfma_kernel(
    const float* __restrict__ qkv, const float* __restrict__ invq,
    const float* __restrict__ invk, const float* __restrict__ temp,
    float* __restrict__ o) {
  __shared__ unsigned short Ks[64][72];    // [key][d]
  __shared__ unsigned short Vts[64][72];   // [d][key]
  __shared__ unsigned short Ps[4][16][72]; // per-wave [row][key]

  const int tid = threadIdx.x;
  const int w = tid >> 6, lane = tid & 63;
  const int qgrp = lane >> 4, lcol = lane & 15;
  const int bh = blockIdx.x >> 4;          // b*NH + h
  const int qt = blockIdx.x & 15;
  const int b = bh >> 3, h = bh & 7;
  const int q0 = qt * 64;

  // ---- Q A-frags with folded scale: q * invq[d] * invk[d] * temp
  short8 qf[2];
  {
    const int m = q0 + w * 16 + lcol;
    const float* qrow = qkv + ((size_t)(b * HW_ + m)) * C3_ + h * 64;
    const float tmp = temp[h];
#pragma unroll
    for (int kc = 0; kc < 2; kc++) {
      const int k0 = kc * 32 + qgrp * 8;
      union { short8 v; unsigned short u[8]; } pk;
#pragma unroll
      for (int j = 0; j < 8; j++) {
        int d = k0 + j;
        float s = invq[bh * 64 + d] * invk[bh * 64 + d] * tmp;
        pk.u[j] = f2bf(qrow[d] * s);
      }
      qf[kc] = pk.v;
    }
  }

  f32x4 of[4];
  float mo[4], lo[4];
#pragma unroll
  for (int nt = 0; nt < 4; nt++) of[nt] = (f32x4){0.f, 0.f, 0.f, 0.f};
#pragma unroll
  for (int r = 0; r < 4; r++) { mo[r] = -1e30f; lo[r] = 0.f; }

  const float* kg = qkv + (size_t)b * HW_ * C3_ + C_ + h * 64;

  for (int kt = 0; kt < 16; kt++) {
    __syncthreads();
    // ---- stage K (row-major) and V^T (d-major) as bf16
#pragma unroll
    for (int i = 0; i < 4; i++) {
      int idx = tid + i * 256;               // 0..1023
      int row = idx >> 4, c4 = (idx & 15) * 4;
      const float* src = kg + (size_t)(kt * 64 + row) * C3_ + c4;
      float4 kv4 = *(const float4*)src;
      float4 vv4 = *(const float4*)(src + C_);
      unsigned short kb[4] = {f2bf(kv4.x), f2bf(kv4.y), f2bf(kv4.z),
                              f2bf(kv4.w)};
      *(uint2*)&Ks[row][c4] = *(const uint2*)kb;
      Vts[c4 + 0][row] = f2bf(vv4.x);
      Vts[c4 + 1][row] = f2bf(vv4.y);
      Vts[c4 + 2][row] = f2bf(vv4.z);
      Vts[c4 + 3][row] = f2bf(vv4.w);
    }
    __syncthreads();

    // ---- S = Q K^T (each wave: 16 rows x 64 keys)
    f32x4 sfr[4];
#pragma unroll
    for (int nt = 0; nt < 4; nt++) sfr[nt] = (f32x4){0.f, 0.f, 0.f, 0.f};
#pragma unroll
    for (int kc = 0; kc < 2; kc++) {
#pragma unroll
      for (int nt = 0; nt < 4; nt++) {
        short8 kf = *(const short8*)&Ks[nt * 16 + lcol][kc * 32 + qgrp * 8];
        sfr[nt] =
            __builtin_amdgcn_mfma_f32_16x16x32_bf16(qf[kc], kf, sfr[nt], 0, 0, 0);
      }
    }

    // ---- online softmax update (row = qgrp*4 + r)
#pragma unroll
    for (int r = 0; r < 4; r++) {
      float mx = fmaxf(fmaxf(sfr[0][r], sfr[1][r]),
                       fmaxf(sfr[2][r], sfr[3][r]));
      mx = fmaxf(mx, __shfl_xor(mx, 1));
      mx = fmaxf(mx, __shfl_xor(mx, 2));
      mx = fmaxf(mx, __shfl_xor(mx, 4));
      mx = fmaxf(mx, __shfl_xor(mx, 8));
      float mn = fmaxf(mo[r], mx);
      float alpha = __expf(mo[r] - mn);
      float rs = 0.f;
#pragma unroll
      for (int nt = 0; nt < 4; nt++) {
        float e = __expf(sfr[nt][r] - mn);
        sfr[nt][r] = e;
        rs += e;
      }
      rs += __shfl_xor(rs, 1);
      rs += __shfl_xor(rs, 2);
      rs += __shfl_xor(rs, 4);
      rs += __shfl_xor(rs, 8);
      lo[r] = lo[r] * alpha + rs;
      mo[r] = mn;
#pragma unroll
      for (int nt = 0; nt < 4; nt++) of[nt][r] *= alpha;
    }

    // ---- P: C-layout -> LDS -> A-layout (per-wave region, no barrier)
#pragma unroll
    for (int nt = 0; nt < 4; nt++)
#pragma unroll
      for (int r = 0; r < 4; r++)
        Ps[w][qgrp * 4 + r][nt * 16 + lcol] = f2bf(sfr[nt][r]);

    // ---- O += P V
#pragma unroll
    for (int kc = 0; kc < 2; kc++) {
      short8 pf = *(const short8*)&Ps[w][lcol][kc * 32 + qgrp * 8];
#pragma unroll
      for (int nt = 0; nt < 4; nt++) {
        short8 vf = *(const short8*)&Vts[nt * 16 + lcol][kc * 32 + qgrp * 8];
        of[nt] =
            __builtin_amdgcn_mfma_f32_16x16x32_bf16(pf, vf, of[nt], 0, 0, 0);
      }
    }
  }

  // ---- epilogue: O / l, write token-major [token][C]
  float inv[4];
#pragma unroll
  for (int r = 0; r < 4; r++) inv[r] = 1.0f / lo[r];
#pragma unroll
  for (int nt = 0; nt < 4; nt++) {
#pragma unroll
    for (int r = 0; r < 4; r++) {
      int m = q0 + w * 16 + qgrp * 4 + r;
      o[((size_t)(b * HW_ + m)) * C_ + h * 64 + nt * 16 + lcol] =
          of[nt][r] * inv[r];
    }
  }
}

// -------------------------------------------------------------------------
// K6: LayerNorm over C per token + residual add of x (NCHW), output token-major
__global__ void ln_residual_kernel(const float* __restrict__ po,
                                   const float* __restrict__ x,
                                   const float* __restrict__ g,
                                   const float* __restrict__ bb,
                                   float* __restrict__ y) {
  int token = blockIdx.x;  // b*HW + n
  int b = token >> 10, n = token & (HW_ - 1);
  int t = threadIdx.x;
  const float* row = po + (size_t)token * C_;
  float v0 = row[t], v1 = row[t + 256];
  float s = v0 + v1;
#pragma unroll
  for (int off = 32; off; off >>= 1) s += __shfl_xor(s, off);
  __shared__ float wr[4];
  if ((t & 63) == 0) wr[t >> 6] = s;
  __syncthreads();
  float mu = (wr[0] + wr[1] + wr[2] + wr[3]) * (1.0f / C_);
  float d0 = v0 - mu, d1 = v1 - mu;
  float vs = d0 * d0 + d1 * d1;
#pragma unroll
  for (int off = 32; off; off >>= 1) vs += __shfl_xor(vs, off);
  __syncthreads();
  if ((t & 63) == 0) wr[t >> 6] = vs;
  __syncthreads();
  float var = (wr[0] + wr[1] + wr[2] + wr[3]) * (1.0f / C_);
  float rstd = rsqrtf(var + 1e-5f);
  float o0 = d0 * rstd * g[t] + bb[t] + x[((size_t)(b * C_ + t)) * HW_ + n];
  float o1 = d1 * rstd * g[t + 256] + bb[t + 256] +
             x[((size_t)(b * C_ + t + 256)) * HW_ + n];
  y[(size_t)token * C_ + t] = o0;
  y[(size_t)token * C_ + t + 256] = o1;
}

// -------------------------------------------------------------------------
// K7: depthwise 3x3 SAME on token-major y -> token-major out (+dw bias)
__global__ void dwconv_kernel(const float* __restrict__ y,
                              const float* __restrict__ w,
                              const float* __restrict__ bias,
                              float* __restrict__ out) {
  int token = blockIdx.x;  // b*HW + s
  int b = token >> 10, s = token & (HW_ - 1);
  int hh = s >> 5, ww = s & 31;
  int t = threadIdx.x;
  for (int c = t; c < C_; c += 256) {
    float acc = bias[c];
#pragma unroll
    for (int ky = 0; ky < 3; ky++) {
      int yy = hh + ky - 1;
      if (yy < 0 || yy >= HH_) continue;
#pragma unroll
      for (int kx = 0; kx < 3; kx++) {
        int xx = ww + kx - 1;
        if (xx < 0 || xx >= WW_) continue;
        acc += w[c * 9 + ky * 3 + kx] *
               y[((size_t)(b * HW_ + yy * 32 + xx)) * C_ + c];
      }
    }
    out[(size_t)token * C_ + c] = acc;
  }
}

// -------------------------------------------------------------------------
extern "C" void kernel_launch(void* const* d_in, const int* in_sizes, int n_in,
                              void* d_out, int out_size, void* d_ws,
                              size_t ws_size, hipStream_t stream) {
  const float* x = (const float*)d_in[0];
  const float* qkv_w = (const float*)d_in[1];
  const float* proj_w = (const float*)d_in[2];
  const float* proj_b = (const float*)d_in[3];
  const float* temperature = (const float*)d_in[4];
  const float* ln_g = (const float*)d_in[5];
  const float* ln_b = (const float*)d_in[6];
  const float* pos = (const float*)d_in[7];
  const float* dw_w = (const float*)d_in[8];
  const float* dw_b = (const float*)d_in[9];
  const float* pw_w = (const float*)d_in[10];
  const float* pw_b = (const float*)d_in[11];
  float* out = (float*)d_out;

  float* ws = (float*)d_ws;
  float* bufA = ws;
  float* bufB = ws + (size_t)12 * 1024 * 1024;
  float* invq = bufB + (size_t)4 * 1024 * 1024;
  float* invk = invq + BB_ * NH_ * DH_;

  const int M = BB_ * HW_;  // 8192 tokens

  // 1) t = transpose(x) + pos_embed              -> bufB
  add_pos_kernel<<<M * C_ / 256, 256, 0, stream>>>(x, pos, bufB);
  // 2) qkv = t @ qkv_w^T                          -> bufA [8192,1536]
  gemm_nt<0><<<dim3(C3_ / 64, M / 64), 256, 0, stream>>>(
      bufB, qkv_w, nullptr, bufA, nullptr, C3_, C_);
  // 3) token-axis L2 norms of q,k
  qk_norms_kernel<<<BB_ * NH_, 256, 0, stream>>>(bufA, invq, invk);
  // 4) MFMA flash attention                       -> bufB [8192,512]
  attn_mfma_kernel<<<BB_ * NH_ * (HW_ / 64), 256, 0, stream>>>(
      bufA, invq, invk, temperature, bufB);
  // 5) proj: o @ proj_w^T + proj_b                -> bufA[0..4M)
  gemm_nt<0><<<dim3(C_ / 64, M / 64), 256, 0, stream>>>(
      bufB, proj_w, proj_b, bufA, nullptr, C_, C_);
  // 6) LayerNorm + residual(x)                    -> bufB (token-major y)
  ln_residual_kernel<<<M, 256, 0, stream>>>(bufA, x, ln_g, ln_b, bufB);
  // 7) depthwise 3x3 + dw_b                       -> bufA[0..4M)
  dwconv_kernel<<<M, 256, 0, stream>>>(bufB, dw_w, dw_b, bufA);
  // 8) pointwise 1x1 + pw_b + residual(y), NCHW   -> d_out
  gemm_nt<1><<<dim3(C_ / 64, M / 64), 256, 0, stream>>>(
      bufA, pw_w, pw_b, out, bufB, C_, C_);
}

// Round 3
// 387.547 us; speedup vs baseline: 4.2698x; 2.0665x over previous
//
#include <hip/hip_runtime.h>
#include <math.h>

// Problem constants
#define BB_ 8
#define C_ 512
#define C3_ 1536
#define HW_ 1024
#define NH_ 8
#define DH_ 64
#define HH_ 32
#define WW_ 32

typedef __attribute__((ext_vector_type(8))) short short8;
typedef __attribute__((ext_vector_type(8))) unsigned short ushort8;
typedef __attribute__((ext_vector_type(4))) float f32x4;
typedef unsigned short ushort;

__device__ inline ushort f2bf(float f) {
  union { float f; unsigned u; } v;
  v.f = f;
  unsigned r = v.u + 0x7fffu + ((v.u >> 16) & 1u);
  return (ushort)(r >> 16);
}
__device__ inline float bf2f(ushort u) {
  union { unsigned u; float f; } v;
  v.u = ((unsigned)u) << 16;
  return v.f;
}

#define GLD16(gptr, lptr)                                                     \
  __builtin_amdgcn_global_load_lds(                                           \
      (const __attribute__((address_space(1))) unsigned int*)(gptr),          \
      (__attribute__((address_space(3))) unsigned int*)(lptr), 16, 0, 0)

// -------------------------------------------------------------------------
// K0: convert weights to bf16 (qkv_w | proj_w | pw_w concatenated)
__global__ void cvt_weights_kernel(const float* __restrict__ qkv_w,
                                   const float* __restrict__ proj_w,
                                   const float* __restrict__ pw_w,
                                   ushort* __restrict__ dst) {
  int i = blockIdx.x * 256 + threadIdx.x;
  if (i < 786432) dst[i] = f2bf(qkv_w[i]);
  else if (i < 1048576) dst[i] = f2bf(proj_w[i - 786432]);
  else dst[i] = f2bf(pw_w[i - 1048576]);
}

// -------------------------------------------------------------------------
// K1: t[b,n,c] = bf16(x[b,c,n] + pos[n,c])
__global__ void add_pos_kernel(const float* __restrict__ x,
                               const float* __restrict__ pos,
                               ushort* __restrict__ t) {
  int idx = blockIdx.x * 256 + threadIdx.x;  // B*HW*C = 4M
  int c = idx & (C_ - 1);
  int bn = idx >> 9;
  int n = bn & (HW_ - 1);
  int b = bn >> 10;
  t[idx] = f2bf(x[((size_t)(b * C_ + c)) * HW_ + n] + pos[n * C_ + c]);
}

// -------------------------------------------------------------------------
// bf16 MFMA GEMM: out[m,j] = sum_k A[m,k]*W[j,k] (+bias[j]).
// 128x128 tile / block, 4 waves (each 64x64), BK=32, global_load_lds
// staging with global-side k-quarter swizzle (conflict-free ds_read_b128).
// EPI 0: bf16 token-major. EPI 1: f32 +bias token-major.
// EPI 2: f32 +bias +resid, NCHW transpose store.
template <int EPI>
__global__ __launch_bounds__(256) void gemm_bf16(
    const ushort* __restrict__ A, const ushort* __restrict__ Wm,
    const float* __restrict__ bias, void* __restrict__ outv,
    const float* __restrict__ resid, int N, int K) {
  __shared__ alignas(16) ushort As[128 * 32];
  __shared__ alignas(16) ushort Bs[128 * 32];
  const int bn = blockIdx.x * 128, bm = blockIdx.y * 128;
  const int tid = threadIdx.x;
  const int w = tid >> 6, lane = tid & 63;
  const int wm = 64 * (w & 1), wn = 64 * (w >> 1);
  const int l15 = lane & 15, lq = lane >> 4;

  f32x4 acc[4][4];
#pragma unroll
  for (int i = 0; i < 4; i++)
#pragma unroll
    for (int j = 0; j < 4; j++) acc[i][j] = (f32x4){0.f, 0.f, 0.f, 0.f};

  // staging lane coords (chunk = 16B = 8 bf16): row within 16-row group,
  // swizzled k-quarter on the global side
  const int srr = lane >> 2, sq1 = lane & 3;

  for (int k0 = 0; k0 < K; k0 += 32) {
    __syncthreads();
#pragma unroll
    for (int j = 0; j < 2; j++) {
      int r = 32 * w + 16 * j + srr;
      int q = (sq1 - (r >> 1)) & 3;
      GLD16(A + (size_t)(bm + r) * K + k0 + q * 8, &As[(32 * w + 16 * j) * 32]);
      GLD16(Wm + (size_t)(bn + r) * K + k0 + q * 8, &Bs[(32 * w + 16 * j) * 32]);
    }
    __syncthreads();
    short8 af[4], bf[4];
#pragma unroll
    for (int nt = 0; nt < 4; nt++) {
      int r = wm + nt * 16 + l15;
      af[nt] = *(const short8*)&As[r * 32 + (((lq + (r >> 1)) & 3) * 8)];
      int c = wn + nt * 16 + l15;
      bf[nt] = *(const short8*)&Bs[c * 32 + (((lq + (c >> 1)) & 3) * 8)];
    }
#pragma unroll
    for (int i = 0; i < 4; i++)
#pragma unroll
      for (int j = 0; j < 4; j++)
        acc[i][j] = __builtin_amdgcn_mfma_f32_16x16x32_bf16(af[i], bf[j],
                                                            acc[i][j], 0, 0, 0);
  }

#pragma unroll
  for (int i = 0; i < 4; i++) {
#pragma unroll
    for (int j = 0; j < 4; j++) {
      int c = bn + wn + j * 16 + l15;
#pragma unroll
      for (int r = 0; r < 4; r++) {
        int m = bm + wm + i * 16 + lq * 4 + r;
        float v = acc[i][j][r];
        if (EPI == 0) {
          ((ushort*)outv)[(size_t)m * N + c] = f2bf(v);
        } else if (EPI == 1) {
          ((float*)outv)[(size_t)m * N + c] = v + bias[c];
        } else {
          int b = m >> 10, s = m & (HW_ - 1);
          ((float*)outv)[((size_t)(b * C_ + c)) * HW_ + s] =
              v + bias[c] + resid[(size_t)m * C_ + c];
        }
      }
    }
  }
}

// -------------------------------------------------------------------------
// K3: per (b,h,d) token-axis L2 norms of q and k -> reciprocal
__global__ void qk_norms_kernel(const ushort* __restrict__ qkv,
                                float* __restrict__ invq,
                                float* __restrict__ invk) {
  int bh = blockIdx.x;
  int b = bh >> 3, h = bh & 7;
  int d = threadIdx.x & 63, g = threadIdx.x >> 6;
  float sq = 0.f, sk = 0.f;
  const ushort* base = qkv + (size_t)b * HW_ * C3_ + h * 64 + d;
  for (int n = g; n < HW_; n += 4) {
    float qv = bf2f(base[(size_t)n * C3_]);
    float kv = bf2f(base[(size_t)n * C3_ + C_]);
    sq += qv * qv;
    sk += kv * kv;
  }
  __shared__ float smq[4][64], smk[4][64];
  smq[g][d] = sq;
  smk[g][d] = sk;
  __syncthreads();
  if (threadIdx.x < 64) {
    float q2 = smq[0][d] + smq[1][d] + smq[2][d] + smq[3][d];
    float k2 = smk[0][d] + smk[1][d] + smk[2][d] + smk[3][d];
    invq[bh * 64 + d] = 1.0f / fmaxf(sqrtf(q2), 1e-12f);
    invk[bh * 64 + d] = 1.0f / fmaxf(sqrtf(k2), 1e-12f);
  }
}

// -------------------------------------------------------------------------
// K4: MFMA flash attention (bf16 in/out). Block = 4 waves = 64-query tile.
__global__ __launch_bounds__(256) void attn_mfma_kernel(
    const ushort* __restrict__ qkv, const float* __restrict__ invq,
    const float* __restrict__ invk, const float* __restrict__ temp,
    ushort* __restrict__ o) {
  __shared__ alignas(16) ushort Ks[64][88];     // [key][d]
  __shared__ alignas(16) ushort Vts[64][88];    // [d][key]
  __shared__ alignas(16) ushort Ps[4][16][88];  // per-wave [row][key]

  const int tid = threadIdx.x;
  const int w = tid >> 6, lane = tid & 63;
  const int qgrp = lane >> 4, lcol = lane & 15;
  const int bh = blockIdx.x >> 4;
  const int qt = blockIdx.x & 15;
  const int b = bh >> 3, h = bh & 7;
  const int q0 = qt * 64;

  short8 qf[2];
  {
    const int m = q0 + w * 16 + lcol;
    const ushort* qrow = qkv + ((size_t)(b * HW_ + m)) * C3_ + h * 64;
    const float tmp = temp[h];
#pragma unroll
    for (int kc = 0; kc < 2; kc++) {
      union { short8 v; ushort u[8]; } pk;
#pragma unroll
      for (int j = 0; j < 8; j++) {
        int d = kc * 32 + qgrp * 8 + j;
        float s = invq[bh * 64 + d] * invk[bh * 64 + d] * tmp;
        pk.u[j] = f2bf(bf2f(qrow[d]) * s);
      }
      qf[kc] = pk.v;
    }
  }

  f32x4 of[4];
  float mo[4], lo[4];
#pragma unroll
  for (int nt = 0; nt < 4; nt++) of[nt] = (f32x4){0.f, 0.f, 0.f, 0.f};
#pragma unroll
  for (int r = 0; r < 4; r++) { mo[r] = -1e30f; lo[r] = 0.f; }

  const ushort* kg = qkv + (size_t)b * HW_ * C3_ + C_ + h * 64;

  for (int kt = 0; kt < 16; kt++) {
    __syncthreads();
#pragma unroll
    for (int i = 0; i < 2; i++) {
      int idx = tid + i * 256;  // 512 chunks of 8 bf16
      int row = idx >> 3, ch = (idx & 7) * 8;
      const ushort* src = kg + (size_t)(kt * 64 + row) * C3_ + ch;
      ushort8 kv = *(const ushort8*)src;
      ushort8 vv = *(const ushort8*)(src + C_);
      *(ushort8*)&Ks[row][ch] = kv;
#pragma unroll
      for (int j = 0; j < 8; j++) Vts[ch + j][row] = vv[j];
    }
    __syncthreads();

    f32x4 sfr[4];
#pragma unroll
    for (int nt = 0; nt < 4; nt++) sfr[nt] = (f32x4){0.f, 0.f, 0.f, 0.f};
#pragma unroll
    for (int kc = 0; kc < 2; kc++) {
#pragma unroll
      for (int nt = 0; nt < 4; nt++) {
        short8 kf = *(const short8*)&Ks[nt * 16 + lcol][kc * 32 + qgrp * 8];
        sfr[nt] =
            __builtin_amdgcn_mfma_f32_16x16x32_bf16(qf[kc], kf, sfr[nt], 0, 0, 0);
      }
    }

#pragma unroll
    for (int r = 0; r < 4; r++) {
      float mx = fmaxf(fmaxf(sfr[0][r], sfr[1][r]),
                       fmaxf(sfr[2][r], sfr[3][r]));
      mx = fmaxf(mx, __shfl_xor(mx, 1));
      mx = fmaxf(mx, __shfl_xor(mx, 2));
      mx = fmaxf(mx, __shfl_xor(mx, 4));
      mx = fmaxf(mx, __shfl_xor(mx, 8));
      float mn = fmaxf(mo[r], mx);
      float alpha = __expf(mo[r] - mn);
      float rs = 0.f;
#pragma unroll
      for (int nt = 0; nt < 4; nt++) {
        float e = __expf(sfr[nt][r] - mn);
        sfr[nt][r] = e;
        rs += e;
      }
      rs += __shfl_xor(rs, 1);
      rs += __shfl_xor(rs, 2);
      rs += __shfl_xor(rs, 4);
      rs += __shfl_xor(rs, 8);
      lo[r] = lo[r] * alpha + rs;
      mo[r] = mn;
#pragma unroll
      for (int nt = 0; nt < 4; nt++) of[nt][r] *= alpha;
    }

#pragma unroll
    for (int nt = 0; nt < 4; nt++)
#pragma unroll
      for (int r = 0; r < 4; r++)
        Ps[w][qgrp * 4 + r][nt * 16 + lcol] = f2bf(sfr[nt][r]);

#pragma unroll
    for (int kc = 0; kc < 2; kc++) {
      short8 pf = *(const short8*)&Ps[w][lcol][kc * 32 + qgrp * 8];
#pragma unroll
      for (int nt = 0; nt < 4; nt++) {
        short8 vf = *(const short8*)&Vts[nt * 16 + lcol][kc * 32 + qgrp * 8];
        of[nt] =
            __builtin_amdgcn_mfma_f32_16x16x32_bf16(pf, vf, of[nt], 0, 0, 0);
      }
    }
  }

  float inv[4];
#pragma unroll
  for (int r = 0; r < 4; r++) inv[r] = 1.0f / lo[r];
#pragma unroll
  for (int nt = 0; nt < 4; nt++) {
#pragma unroll
    for (int r = 0; r < 4; r++) {
      int m = q0 + w * 16 + qgrp * 4 + r;
      o[((size_t)(b * HW_ + m)) * C_ + h * 64 + nt * 16 + lcol] =
          f2bf(of[nt][r] * inv[r]);
    }
  }
}

// -------------------------------------------------------------------------
// K6: LayerNorm + residual(x). po updated IN PLACE to f32 y; also writes
// bf16 copy for the dwconv/pw chain.
__global__ void ln_residual_kernel(float* __restrict__ po,
                                   const float* __restrict__ x,
                                   const float* __restrict__ g,
                                   const float* __restrict__ bb,
                                   ushort* __restrict__ ybf) {
  int token = blockIdx.x;
  int b = token >> 10, n = token & (HW_ - 1);
  int t = threadIdx.x;
  float* row = po + (size_t)token * C_;
  float v0 = row[t], v1 = row[t + 256];
  float s = v0 + v1;
#pragma unroll
  for (int off = 32; off; off >>= 1) s += __shfl_xor(s, off);
  __shared__ float wr[4];
  if ((t & 63) == 0) wr[t >> 6] = s;
  __syncthreads();
  float mu = (wr[0] + wr[1] + wr[2] + wr[3]) * (1.0f / C_);
  float d0 = v0 - mu, d1 = v1 - mu;
  float vs = d0 * d0 + d1 * d1;
#pragma unroll
  for (int off = 32; off; off >>= 1) vs += __shfl_xor(vs, off);
  __syncthreads();
  if ((t & 63) == 0) wr[t >> 6] = vs;
  __syncthreads();
  float var = (wr[0] + wr[1] + wr[2] + wr[3]) * (1.0f / C_);
  float rstd = rsqrtf(var + 1e-5f);
  float o0 = d0 * rstd * g[t] + bb[t] + x[((size_t)(b * C_ + t)) * HW_ + n];
  float o1 = d1 * rstd * g[t + 256] + bb[t + 256] +
             x[((size_t)(b * C_ + t + 256)) * HW_ + n];
  row[t] = o0;
  row[t + 256] = o1;
  ybf[(size_t)token * C_ + t] = f2bf(o0);
  ybf[(size_t)token * C_ + t + 256] = f2bf(o1);
}

// -------------------------------------------------------------------------
// K7: depthwise 3x3 SAME on token-major bf16 y -> bf16 out (+dw bias)
__global__ void dwconv_kernel(const ushort* __restrict__ y,
                              const float* __restrict__ w,
                              const float* __restrict__ bias,
                              ushort* __restrict__ out) {
  int token = blockIdx.x;
  int b = token >> 10, s = token & (HW_ - 1);
  int hh = s >> 5, ww = s & 31;
  int t = threadIdx.x;
  for (int c = t; c < C_; c += 256) {
    float acc = bias[c];
#pragma unroll
    for (int ky = 0; ky < 3; ky++) {
      int yy = hh + ky - 1;
      if (yy < 0 || yy >= HH_) continue;
#pragma unroll
      for (int kx = 0; kx < 3; kx++) {
        int xx = ww + kx - 1;
        if (xx < 0 || xx >= WW_) continue;
        acc += w[c * 9 + ky * 3 + kx] *
               bf2f(y[((size_t)(b * HW_ + yy * 32 + xx)) * C_ + c]);
      }
    }
    out[(size_t)token * C_ + c] = f2bf(acc);
  }
}

// -------------------------------------------------------------------------
extern "C" void kernel_launch(void* const* d_in, const int* in_sizes, int n_in,
                              void* d_out, int out_size, void* d_ws,
                              size_t ws_size, hipStream_t stream) {
  const float* x = (const float*)d_in[0];
  const float* qkv_w = (const float*)d_in[1];
  const float* proj_w = (const float*)d_in[2];
  const float* proj_b = (const float*)d_in[3];
  const float* temperature = (const float*)d_in[4];
  const float* ln_g = (const float*)d_in[5];
  const float* ln_b = (const float*)d_in[6];
  const float* pos = (const float*)d_in[7];
  const float* dw_w = (const float*)d_in[8];
  const float* dw_b = (const float*)d_in[9];
  const float* pw_w = (const float*)d_in[10];
  const float* pw_b = (const float*)d_in[11];
  float* out = (float*)d_out;

  float* ws = (float*)d_ws;
  // [0,24MB)   qkv_bf
  // [24,32MB)  t_bf -> attn_out_bf -> dw_out_bf
  // [32,48MB)  proj_out f32 -> y f32 (LN in-place)
  // [48,56MB)  y_bf
  // [56,~59MB) weights bf16; then invq/invk
  ushort* qkv_bf = (ushort*)ws;
  ushort* t_bf = (ushort*)(ws + (size_t)6 * 1024 * 1024);
  float* proj_out = ws + (size_t)8 * 1024 * 1024;
  ushort* y_bf = (ushort*)(ws + (size_t)12 * 1024 * 1024);
  ushort* wts = (ushort*)(ws + (size_t)14 * 1024 * 1024);
  ushort* qkvw_bf = wts;
  ushort* projw_bf = wts + 786432;
  ushort* pww_bf = wts + 1048576;
  float* invq = ws + (size_t)15 * 1024 * 1024;
  float* invk = invq + 512;

  const int M = BB_ * HW_;  // 8192 tokens

  // 0) weights -> bf16
  cvt_weights_kernel<<<1310720 / 256, 256, 0, stream>>>(qkv_w, proj_w, pw_w,
                                                        wts);
  // 1) t = bf16(transpose(x) + pos)
  add_pos_kernel<<<M * C_ / 256, 256, 0, stream>>>(x, pos, t_bf);
  // 2) qkv GEMM (bf16 out)
  gemm_bf16<0><<<dim3(C3_ / 128, M / 128), 256, 0, stream>>>(
      t_bf, qkvw_bf, nullptr, qkv_bf, nullptr, C3_, C_);
  // 3) q/k token-axis norms
  qk_norms_kernel<<<BB_ * NH_, 256, 0, stream>>>(qkv_bf, invq, invk);
  // 4) flash attention -> attn_out (bf16, reuses t region)
  attn_mfma_kernel<<<BB_ * NH_ * (HW_ / 64), 256, 0, stream>>>(
      qkv_bf, invq, invk, temperature, t_bf);
  // 5) proj GEMM (+bias, f32 out)
  gemm_bf16<1><<<dim3(C_ / 128, M / 128), 256, 0, stream>>>(
      t_bf, projw_bf, proj_b, proj_out, nullptr, C_, C_);
  // 6) LayerNorm + residual(x): proj_out -> y (in place) + y_bf
  ln_residual_kernel<<<M, 256, 0, stream>>>(proj_out, x, ln_g, ln_b, y_bf);
  // 7) depthwise 3x3 -> dw_out (bf16, reuses t region)
  dwconv_kernel<<<M, 256, 0, stream>>>(y_bf, dw_w, dw_b, t_bf);
  // 8) pointwise GEMM + pw_b + residual(y), NCHW -> out
  gemm_bf16<2><<<dim3(C_ / 128, M / 128), 256, 0, stream>>>(
      t_bf, pww_bf, pw_b, out, proj_out, C_, C_);
}

// Round 4
// 238.457 us; speedup vs baseline: 6.9394x; 1.6252x over previous
//
#include <hip/hip_runtime.h>
#include <math.h>

// Problem constants
#define BB_ 8
#define C_ 512
#define C3_ 1536
#define HW_ 1024
#define NH_ 8
#define DH_ 64
#define HH_ 32
#define WW_ 32

typedef __attribute__((ext_vector_type(8))) short short8;
typedef __attribute__((ext_vector_type(8))) unsigned short ushort8;
typedef __attribute__((ext_vector_type(4))) unsigned short ushort4_t;
typedef __attribute__((ext_vector_type(4))) float f32x4;
typedef unsigned short ushort;

__device__ inline ushort f2bf(float f) {
  union { float f; unsigned u; } v;
  v.f = f;
  unsigned r = v.u + 0x7fffu + ((v.u >> 16) & 1u);
  return (ushort)(r >> 16);
}
__device__ inline float bf2f(ushort u) {
  union { unsigned u; float f; } v;
  v.u = ((unsigned)u) << 16;
  return v.f;
}

#define GLD16(gptr, lptr)                                                     \
  __builtin_amdgcn_global_load_lds(                                           \
      (const __attribute__((address_space(1))) unsigned int*)(gptr),          \
      (__attribute__((address_space(3))) unsigned int*)(lptr), 16, 0, 0)

// -------------------------------------------------------------------------
// K0: convert weights to bf16 (qkv_w | proj_w | pw_w concatenated)
__global__ void cvt_weights_kernel(const float* __restrict__ qkv_w,
                                   const float* __restrict__ proj_w,
                                   const float* __restrict__ pw_w,
                                   ushort* __restrict__ dst) {
  int i = blockIdx.x * 256 + threadIdx.x;
  if (i < 786432) dst[i] = f2bf(qkv_w[i]);
  else if (i < 1048576) dst[i] = f2bf(proj_w[i - 786432]);
  else dst[i] = f2bf(pw_w[i - 1048576]);
}

// -------------------------------------------------------------------------
// K1: tiled transpose. t[b,n,c] = bf16(x[b,c,n] + pos[n,c]); xT[b,n,c]=bf16(x)
__global__ __launch_bounds__(256) void add_pos_kernel(
    const float* __restrict__ x, const float* __restrict__ pos,
    ushort* __restrict__ t, ushort* __restrict__ xT) {
  __shared__ float tile[64][65];
  const int tid = threadIdx.x;
  const int n0 = blockIdx.x * 64, c0 = blockIdx.y * 64, b = blockIdx.z;
  // load: coalesced float4 along n
#pragma unroll
  for (int it = 0; it < 4; it++) {
    int c_l = (tid >> 4) + it * 16;
    int n_l4 = (tid & 15) * 4;
    float4 v = *(const float4*)&x[((size_t)(b * C_ + c0 + c_l)) * HW_ + n0 + n_l4];
    tile[c_l][n_l4 + 0] = v.x;
    tile[c_l][n_l4 + 1] = v.y;
    tile[c_l][n_l4 + 2] = v.z;
    tile[c_l][n_l4 + 3] = v.w;
  }
  __syncthreads();
  // store: coalesced along c
#pragma unroll
  for (int it = 0; it < 4; it++) {
    int n_l = (tid >> 4) + it * 16;
    int c_l4 = (tid & 15) * 4;
    size_t token = (size_t)(b * HW_ + n0 + n_l);
    float4 pv = *(const float4*)&pos[(n0 + n_l) * C_ + c0 + c_l4];
    float xv0 = tile[c_l4 + 0][n_l], xv1 = tile[c_l4 + 1][n_l];
    float xv2 = tile[c_l4 + 2][n_l], xv3 = tile[c_l4 + 3][n_l];
    ushort4_t tb = {f2bf(xv0 + pv.x), f2bf(xv1 + pv.y), f2bf(xv2 + pv.z),
                    f2bf(xv3 + pv.w)};
    ushort4_t xb = {f2bf(xv0), f2bf(xv1), f2bf(xv2), f2bf(xv3)};
    *(ushort4_t*)&t[token * C_ + c0 + c_l4] = tb;
    *(ushort4_t*)&xT[token * C_ + c0 + c_l4] = xb;
  }
}

// -------------------------------------------------------------------------
// bf16 MFMA GEMM (m97 structure): 128x128 tile, 4 waves, BK=32,
// global_load_lds staging with global-side k-quarter swizzle.
template <int EPI>
__global__ __launch_bounds__(256) void gemm_bf16(
    const ushort* __restrict__ A, const ushort* __restrict__ Wm,
    const float* __restrict__ bias, void* __restrict__ outv,
    const float* __restrict__ resid, int N, int K) {
  __shared__ alignas(16) ushort As[128 * 32];
  __shared__ alignas(16) ushort Bs[128 * 32];
  const int bn = blockIdx.x * 128, bm = blockIdx.y * 128;
  const int tid = threadIdx.x;
  const int w = tid >> 6, lane = tid & 63;
  const int wm = 64 * (w & 1), wn = 64 * (w >> 1);
  const int l15 = lane & 15, lq = lane >> 4;

  f32x4 acc[4][4];
#pragma unroll
  for (int i = 0; i < 4; i++)
#pragma unroll
    for (int j = 0; j < 4; j++) acc[i][j] = (f32x4){0.f, 0.f, 0.f, 0.f};

  const int srr = lane >> 2, sq1 = lane & 3;

  for (int k0 = 0; k0 < K; k0 += 32) {
    __syncthreads();
#pragma unroll
    for (int j = 0; j < 2; j++) {
      int r = 32 * w + 16 * j + srr;
      int q = (sq1 - (r >> 1)) & 3;
      GLD16(A + (size_t)(bm + r) * K + k0 + q * 8, &As[(32 * w + 16 * j) * 32]);
      GLD16(Wm + (size_t)(bn + r) * K + k0 + q * 8, &Bs[(32 * w + 16 * j) * 32]);
    }
    __syncthreads();
    short8 af[4], bf[4];
#pragma unroll
    for (int nt = 0; nt < 4; nt++) {
      int r = wm + nt * 16 + l15;
      af[nt] = *(const short8*)&As[r * 32 + (((lq + (r >> 1)) & 3) * 8)];
      int c = wn + nt * 16 + l15;
      bf[nt] = *(const short8*)&Bs[c * 32 + (((lq + (c >> 1)) & 3) * 8)];
    }
#pragma unroll
    for (int i = 0; i < 4; i++)
#pragma unroll
      for (int j = 0; j < 4; j++)
        acc[i][j] = __builtin_amdgcn_mfma_f32_16x16x32_bf16(af[i], bf[j],
                                                            acc[i][j], 0, 0, 0);
  }

#pragma unroll
  for (int i = 0; i < 4; i++) {
#pragma unroll
    for (int j = 0; j < 4; j++) {
      int c = bn + wn + j * 16 + l15;
#pragma unroll
      for (int r = 0; r < 4; r++) {
        int m = bm + wm + i * 16 + lq * 4 + r;
        float v = acc[i][j][r];
        if (EPI == 0) {
          ((ushort*)outv)[(size_t)m * N + c] = f2bf(v);
        } else if (EPI == 1) {
          ((float*)outv)[(size_t)m * N + c] = v + bias[c];
        } else {
          int b = m >> 10, s = m & (HW_ - 1);
          ((float*)outv)[((size_t)(b * C_ + c)) * HW_ + s] =
              v + bias[c] + resid[(size_t)m * C_ + c];
        }
      }
    }
  }
}

// -------------------------------------------------------------------------
// K3: per (b,h,d) token-axis L2 norms of q,k -> reciprocal (vectorized)
__global__ __launch_bounds__(256) void qk_norms_kernel(
    const ushort* __restrict__ qkv, float* __restrict__ invq,
    float* __restrict__ invk) {
  __shared__ float smq[32][64], smk[32][64];
  const int bh = blockIdx.x;
  const int b = bh >> 3, h = bh & 7;
  const int tid = threadIdx.x;
  const int tok_off = tid >> 3, chunk = tid & 7;
  float sq[8] = {}, sk[8] = {};
  const ushort* base =
      qkv + (size_t)b * HW_ * C3_ + h * 64 + chunk * 8;
  for (int n = tok_off; n < HW_; n += 32) {
    const ushort* p = base + (size_t)n * C3_;
    ushort8 q8 = *(const ushort8*)p;
    ushort8 k8 = *(const ushort8*)(p + C_);
#pragma unroll
    for (int j = 0; j < 8; j++) {
      float qv = bf2f(q8[j]), kv = bf2f(k8[j]);
      sq[j] += qv * qv;
      sk[j] += kv * kv;
    }
  }
#pragma unroll
  for (int j = 0; j < 8; j++) {
    smq[tok_off][chunk * 8 + j] = sq[j];
    smk[tok_off][chunk * 8 + j] = sk[j];
  }
  __syncthreads();
  if (tid < 64) {
    float s = 0.f;
    for (int i = 0; i < 32; i++) s += smq[i][tid];
    invq[bh * 64 + tid] = 1.0f / fmaxf(sqrtf(s), 1e-12f);
  } else if (tid < 128) {
    int d = tid - 64;
    float s = 0.f;
    for (int i = 0; i < 32; i++) s += smk[i][d];
    invk[bh * 64 + d] = 1.0f / fmaxf(sqrtf(s), 1e-12f);
  }
}

// -------------------------------------------------------------------------
// K4: MFMA flash attention v3. 8 waves = 128 queries/block; fixed-max
// softmax (|score| <= ~0.07 by Cauchy-Schwarz on unit token-columns);
// Vts chunk-XOR swizzle -> transpose writes are 2-way (free).
__global__ __launch_bounds__(512) void attn_mfma_kernel(
    const ushort* __restrict__ qkv, const float* __restrict__ invq,
    const float* __restrict__ invk, const float* __restrict__ temp,
    ushort* __restrict__ o) {
  __shared__ alignas(16) ushort Ks[64][88];     // [key][d]
  __shared__ alignas(16) ushort Vts[64][88];    // [d][key-swizzled]
  __shared__ alignas(16) ushort Ps[8][16][88];  // per-wave [row][key]

  const int tid = threadIdx.x;
  const int w = tid >> 6, lane = tid & 63;
  const int qgrp = lane >> 4, lcol = lane & 15;
  const int bh = blockIdx.x >> 3;
  const int qt = blockIdx.x & 7;
  const int b = bh >> 3, h = bh & 7;
  const int q0 = qt * 128;

  short8 qf[2];
  {
    const int m = q0 + w * 16 + lcol;
    const ushort* qrow = qkv + ((size_t)(b * HW_ + m)) * C3_ + h * 64;
    const float tmp = temp[h];
#pragma unroll
    for (int kc = 0; kc < 2; kc++) {
      union { short8 v; ushort u[8]; } pk;
#pragma unroll
      for (int j = 0; j < 8; j++) {
        int d = kc * 32 + qgrp * 8 + j;
        float s = invq[bh * 64 + d] * invk[bh * 64 + d] * tmp;
        pk.u[j] = f2bf(bf2f(qrow[d]) * s);
      }
      qf[kc] = pk.v;
    }
  }

  f32x4 of[4];
  float lsum[4] = {0.f, 0.f, 0.f, 0.f};
#pragma unroll
  for (int nt = 0; nt < 4; nt++) of[nt] = (f32x4){0.f, 0.f, 0.f, 0.f};

  const ushort* kg = qkv + (size_t)b * HW_ * C3_ + C_ + h * 64;

  // staging coords: 512 threads cover 64 rows x 8 chunks (of 8 bf16)
  const int srow = tid >> 3;
  const int sch = (tid & 7) * 8;
  const int vcol = (((srow >> 3) + (tid & 7)) & 7) * 8 + (srow & 7);

  for (int kt = 0; kt < 16; kt++) {
    __syncthreads();
    {
      const ushort* src = kg + (size_t)(kt * 64 + srow) * C3_ + sch;
      ushort8 kv = *(const ushort8*)src;
      ushort8 vv = *(const ushort8*)(src + C_);
      *(ushort8*)&Ks[srow][sch] = kv;
#pragma unroll
      for (int j = 0; j < 8; j++) Vts[sch + j][vcol] = vv[j];
    }
    __syncthreads();

    f32x4 sfr[4];
#pragma unroll
    for (int nt = 0; nt < 4; nt++) sfr[nt] = (f32x4){0.f, 0.f, 0.f, 0.f};
#pragma unroll
    for (int kc = 0; kc < 2; kc++) {
#pragma unroll
      for (int nt = 0; nt < 4; nt++) {
        short8 kf = *(const short8*)&Ks[nt * 16 + lcol][kc * 32 + qgrp * 8];
        sfr[nt] =
            __builtin_amdgcn_mfma_f32_16x16x32_bf16(qf[kc], kf, sfr[nt], 0, 0, 0);
      }
    }

    // fixed-max softmax: e = exp(s); defer cross-lane sum to epilogue
#pragma unroll
    for (int nt = 0; nt < 4; nt++) {
#pragma unroll
      for (int r = 0; r < 4; r++) {
        float e = __expf(sfr[nt][r]);
        lsum[r] += e;
        Ps[w][qgrp * 4 + r][nt * 16 + lcol] = f2bf(e);
      }
    }

#pragma unroll
    for (int kc = 0; kc < 2; kc++) {
      short8 pf = *(const short8*)&Ps[w][lcol][kc * 32 + qgrp * 8];
#pragma unroll
      for (int nt = 0; nt < 4; nt++) {
        int d = nt * 16 + lcol;
        int cph = ((kc * 4 + qgrp) + (d >> 3)) & 7;
        short8 vf = *(const short8*)&Vts[d][cph * 8];
        of[nt] =
            __builtin_amdgcn_mfma_f32_16x16x32_bf16(pf, vf, of[nt], 0, 0, 0);
      }
    }
  }

  float inv[4];
#pragma unroll
  for (int r = 0; r < 4; r++) {
    float s = lsum[r];
    s += __shfl_xor(s, 1);
    s += __shfl_xor(s, 2);
    s += __shfl_xor(s, 4);
    s += __shfl_xor(s, 8);
    inv[r] = 1.0f / s;
  }
#pragma unroll
  for (int nt = 0; nt < 4; nt++) {
#pragma unroll
    for (int r = 0; r < 4; r++) {
      int m = q0 + w * 16 + qgrp * 4 + r;
      o[((size_t)(b * HW_ + m)) * C_ + h * 64 + nt * 16 + lcol] =
          f2bf(of[nt][r] * inv[r]);
    }
  }
}

// -------------------------------------------------------------------------
// K6: LayerNorm + residual(xT bf16). po updated IN PLACE to f32 y.
__global__ void ln_residual_kernel(float* __restrict__ po,
                                   const ushort* __restrict__ xT,
                                   const float* __restrict__ g,
                                   const float* __restrict__ bb) {
  int token = blockIdx.x;
  int t = threadIdx.x;
  float* row = po + (size_t)token * C_;
  float v0 = row[t], v1 = row[t + 256];
  float s = v0 + v1;
#pragma unroll
  for (int off = 32; off; off >>= 1) s += __shfl_xor(s, off);
  __shared__ float wr[4];
  if ((t & 63) == 0) wr[t >> 6] = s;
  __syncthreads();
  float mu = (wr[0] + wr[1] + wr[2] + wr[3]) * (1.0f / C_);
  float d0 = v0 - mu, d1 = v1 - mu;
  float vs = d0 * d0 + d1 * d1;
#pragma unroll
  for (int off = 32; off; off >>= 1) vs += __shfl_xor(vs, off);
  __syncthreads();
  if ((t & 63) == 0) wr[t >> 6] = vs;
  __syncthreads();
  float var = (wr[0] + wr[1] + wr[2] + wr[3]) * (1.0f / C_);
  float rstd = rsqrtf(var + 1e-5f);
  float o0 = d0 * rstd * g[t] + bb[t] + bf2f(xT[(size_t)token * C_ + t]);
  float o1 = d1 * rstd * g[t + 256] + bb[t + 256] +
             bf2f(xT[(size_t)token * C_ + t + 256]);
  row[t] = o0;
  row[t + 256] = o1;
}

// -------------------------------------------------------------------------
// K7: depthwise 3x3 SAME on f32 y (token-major) -> bf16 out (+dw bias).
// Thread owns 8 channels; weights hoisted to registers; 4 tokens/thread.
__global__ __launch_bounds__(256) void dwconv_kernel(
    const float* __restrict__ y, const float* __restrict__ w,
    const float* __restrict__ bias, ushort* __restrict__ out) {
  const int cg = threadIdx.x & 63, tg = threadIdx.x >> 6;
  const int c0 = cg * 8;
  float wreg[9][8], breg[8];
#pragma unroll
  for (int j = 0; j < 8; j++) {
    breg[j] = bias[c0 + j];
#pragma unroll
    for (int kk = 0; kk < 9; kk++) wreg[kk][j] = w[(c0 + j) * 9 + kk];
  }
  for (int i = 0; i < 4; i++) {
    int token = blockIdx.x * 16 + tg * 4 + i;
    int b = token >> 10, s = token & (HW_ - 1);
    int hh = s >> 5, ww = s & 31;
    float acc[8];
#pragma unroll
    for (int j = 0; j < 8; j++) acc[j] = breg[j];
#pragma unroll
    for (int ky = 0; ky < 3; ky++) {
      int yy = hh + ky - 1;
      if (yy < 0 || yy >= HH_) continue;
#pragma unroll
      for (int kx = 0; kx < 3; kx++) {
        int xx = ww + kx - 1;
        if (xx < 0 || xx >= WW_) continue;
        const float* src = y + ((size_t)(b * HW_ + yy * 32 + xx)) * C_ + c0;
        float4 a = *(const float4*)src;
        float4 bq = *(const float4*)(src + 4);
        const float* wk = wreg[ky * 3 + kx];
        acc[0] += wk[0] * a.x;
        acc[1] += wk[1] * a.y;
        acc[2] += wk[2] * a.z;
        acc[3] += wk[3] * a.w;
        acc[4] += wk[4] * bq.x;
        acc[5] += wk[5] * bq.y;
        acc[6] += wk[6] * bq.z;
        acc[7] += wk[7] * bq.w;
      }
    }
    ushort8 pk;
#pragma unroll
    for (int j = 0; j < 8; j++) pk[j] = f2bf(acc[j]);
    *(ushort8*)&out[(size_t)token * C_ + c0] = pk;
  }
}

// -------------------------------------------------------------------------
extern "C" void kernel_launch(void* const* d_in, const int* in_sizes, int n_in,
                              void* d_out, int out_size, void* d_ws,
                              size_t ws_size, hipStream_t stream) {
  const float* x = (const float*)d_in[0];
  const float* qkv_w = (const float*)d_in[1];
  const float* proj_w = (const float*)d_in[2];
  const float* proj_b = (const float*)d_in[3];
  const float* temperature = (const float*)d_in[4];
  const float* ln_g = (const float*)d_in[5];
  const float* ln_b = (const float*)d_in[6];
  const float* pos = (const float*)d_in[7];
  const float* dw_w = (const float*)d_in[8];
  const float* dw_b = (const float*)d_in[9];
  const float* pw_w = (const float*)d_in[10];
  const float* pw_b = (const float*)d_in[11];
  float* out = (float*)d_out;

  float* ws = (float*)d_ws;
  // [0,6M)f32    qkv_bf (bf16)
  // [6M,8M)      t_bf -> attn_out_bf -> dw_out_bf (bf16)
  // [8M,12M)     proj_out f32 -> y f32 (LN in-place, pw residual)
  // [12M,14M)    xT bf16 (transposed input, residual for LN)
  // [14M,~14.7M) weights bf16; [15M,...) invq/invk
  ushort* qkv_bf = (ushort*)ws;
  ushort* t_bf = (ushort*)(ws + (size_t)6 * 1024 * 1024);
  float* proj_out = ws + (size_t)8 * 1024 * 1024;
  ushort* xT_bf = (ushort*)(ws + (size_t)12 * 1024 * 1024);
  ushort* wts = (ushort*)(ws + (size_t)14 * 1024 * 1024);
  ushort* qkvw_bf = wts;
  ushort* projw_bf = wts + 786432;
  ushort* pww_bf = wts + 1048576;
  float* invq = ws + (size_t)15 * 1024 * 1024;
  float* invk = invq + 512;

  const int M = BB_ * HW_;  // 8192 tokens

  // 0) weights -> bf16
  cvt_weights_kernel<<<1310720 / 256, 256, 0, stream>>>(qkv_w, proj_w, pw_w,
                                                        wts);
  // 1) t = bf16(x^T + pos), xT = bf16(x^T)   (tiled transpose)
  add_pos_kernel<<<dim3(16, 8, 8), 256, 0, stream>>>(x, pos, t_bf, xT_bf);
  // 2) qkv GEMM (bf16 out)
  gemm_bf16<0><<<dim3(C3_ / 128, M / 128), 256, 0, stream>>>(
      t_bf, qkvw_bf, nullptr, qkv_bf, nullptr, C3_, C_);
  // 3) q/k token-axis norms
  qk_norms_kernel<<<BB_ * NH_, 256, 0, stream>>>(qkv_bf, invq, invk);
  // 4) flash attention -> attn_out (bf16, reuses t region)
  attn_mfma_kernel<<<BB_ * NH_ * (HW_ / 128), 512, 0, stream>>>(
      qkv_bf, invq, invk, temperature, t_bf);
  // 5) proj GEMM (+bias, f32 out)
  gemm_bf16<1><<<dim3(C_ / 128, M / 128), 256, 0, stream>>>(
      t_bf, projw_bf, proj_b, proj_out, nullptr, C_, C_);
  // 6) LayerNorm + residual(xT): proj_out -> y (in place)
  ln_residual_kernel<<<M, 256, 0, stream>>>(proj_out, xT_bf, ln_g, ln_b);
  // 7) depthwise 3x3 on f32 y -> dw_out (bf16, reuses t region)
  dwconv_kernel<<<M / 16, 256, 0, stream>>>(proj_out, dw_w, dw_b, t_bf);
  // 8) pointwise GEMM + pw_b + residual(y), NCHW -> out
  gemm_bf16<2><<<dim3(C_ / 128, M / 128), 256, 0, stream>>>(
      t_bf, pww_bf, pw_b, out, proj_out, C_, C_);
}

// Round 5
// 218.521 us; speedup vs baseline: 7.5724x; 1.0912x over previous
//
#include <hip/hip_runtime.h>
#include <math.h>

// Problem constants
#define BB_ 8
#define C_ 512
#define C3_ 1536
#define HW_ 1024
#define NH_ 8
#define DH_ 64
#define HH_ 32
#define WW_ 32

typedef __attribute__((ext_vector_type(8))) short short8;
typedef __attribute__((ext_vector_type(8))) unsigned short ushort8;
typedef __attribute__((ext_vector_type(4))) unsigned short ushort4_t;
typedef __attribute__((ext_vector_type(4))) float f32x4;
typedef unsigned short ushort;

__device__ inline ushort f2bf(float f) {
  union { float f; unsigned u; } v;
  v.f = f;
  unsigned r = v.u + 0x7fffu + ((v.u >> 16) & 1u);
  return (ushort)(r >> 16);
}
__device__ inline float bf2f(ushort u) {
  union { unsigned u; float f; } v;
  v.u = ((unsigned)u) << 16;
  return v.f;
}

#define GLD16(gptr, lptr)                                                     \
  __builtin_amdgcn_global_load_lds(                                           \
      (const __attribute__((address_space(1))) unsigned int*)(gptr),          \
      (__attribute__((address_space(3))) unsigned int*)(lptr), 16, 0, 0)

// -------------------------------------------------------------------------
// K0: convert weights to bf16 (qkv_w | proj_w | pw_w concatenated)
__global__ void cvt_weights_kernel(const float* __restrict__ qkv_w,
                                   const float* __restrict__ proj_w,
                                   const float* __restrict__ pw_w,
                                   ushort* __restrict__ dst) {
  int i = blockIdx.x * 256 + threadIdx.x;
  if (i < 786432) dst[i] = f2bf(qkv_w[i]);
  else if (i < 1048576) dst[i] = f2bf(proj_w[i - 786432]);
  else dst[i] = f2bf(pw_w[i - 1048576]);
}

// -------------------------------------------------------------------------
// K1: tiled transpose. t[b,n,c] = bf16(x[b,c,n] + pos[n,c]); xT[b,n,c]=bf16(x)
__global__ __launch_bounds__(256) void add_pos_kernel(
    const float* __restrict__ x, const float* __restrict__ pos,
    ushort* __restrict__ t, ushort* __restrict__ xT) {
  __shared__ float tile[64][65];
  const int tid = threadIdx.x;
  const int n0 = blockIdx.x * 64, c0 = blockIdx.y * 64, b = blockIdx.z;
#pragma unroll
  for (int it = 0; it < 4; it++) {
    int c_l = (tid >> 4) + it * 16;
    int n_l4 = (tid & 15) * 4;
    float4 v = *(const float4*)&x[((size_t)(b * C_ + c0 + c_l)) * HW_ + n0 + n_l4];
    tile[c_l][n_l4 + 0] = v.x;
    tile[c_l][n_l4 + 1] = v.y;
    tile[c_l][n_l4 + 2] = v.z;
    tile[c_l][n_l4 + 3] = v.w;
  }
  __syncthreads();
#pragma unroll
  for (int it = 0; it < 4; it++) {
    int n_l = (tid >> 4) + it * 16;
    int c_l4 = (tid & 15) * 4;
    size_t token = (size_t)(b * HW_ + n0 + n_l);
    float4 pv = *(const float4*)&pos[(n0 + n_l) * C_ + c0 + c_l4];
    float xv0 = tile[c_l4 + 0][n_l], xv1 = tile[c_l4 + 1][n_l];
    float xv2 = tile[c_l4 + 2][n_l], xv3 = tile[c_l4 + 3][n_l];
    ushort4_t tb = {f2bf(xv0 + pv.x), f2bf(xv1 + pv.y), f2bf(xv2 + pv.z),
                    f2bf(xv3 + pv.w)};
    ushort4_t xb = {f2bf(xv0), f2bf(xv1), f2bf(xv2), f2bf(xv3)};
    *(ushort4_t*)&t[token * C_ + c0 + c_l4] = tb;
    *(ushort4_t*)&xT[token * C_ + c0 + c_l4] = xb;
  }
}

// -------------------------------------------------------------------------
// bf16 MFMA GEMM 128x128 (m97 structure), EPI0: bf16 token-major out.
__global__ __launch_bounds__(256) void gemm_128(
    const ushort* __restrict__ A, const ushort* __restrict__ Wm,
    ushort* __restrict__ out, int N, int K) {
  __shared__ alignas(16) ushort As[128 * 32];
  __shared__ alignas(16) ushort Bs[128 * 32];
  const int bn = blockIdx.x * 128, bm = blockIdx.y * 128;
  const int tid = threadIdx.x;
  const int w = tid >> 6, lane = tid & 63;
  const int wm = 64 * (w & 1), wn = 64 * (w >> 1);
  const int l15 = lane & 15, lq = lane >> 4;

  f32x4 acc[4][4];
#pragma unroll
  for (int i = 0; i < 4; i++)
#pragma unroll
    for (int j = 0; j < 4; j++) acc[i][j] = (f32x4){0.f, 0.f, 0.f, 0.f};

  const int srr = lane >> 2, sq1 = lane & 3;

  for (int k0 = 0; k0 < K; k0 += 32) {
    __syncthreads();
#pragma unroll
    for (int j = 0; j < 2; j++) {
      int r = 32 * w + 16 * j + srr;
      int q = (sq1 - (r >> 1)) & 3;
      GLD16(A + (size_t)(bm + r) * K + k0 + q * 8, &As[(32 * w + 16 * j) * 32]);
      GLD16(Wm + (size_t)(bn + r) * K + k0 + q * 8, &Bs[(32 * w + 16 * j) * 32]);
    }
    __syncthreads();
    short8 af[4], bf[4];
#pragma unroll
    for (int nt = 0; nt < 4; nt++) {
      int r = wm + nt * 16 + l15;
      af[nt] = *(const short8*)&As[r * 32 + (((lq + (r >> 1)) & 3) * 8)];
      int c = wn + nt * 16 + l15;
      bf[nt] = *(const short8*)&Bs[c * 32 + (((lq + (c >> 1)) & 3) * 8)];
    }
#pragma unroll
    for (int i = 0; i < 4; i++)
#pragma unroll
      for (int j = 0; j < 4; j++)
        acc[i][j] = __builtin_amdgcn_mfma_f32_16x16x32_bf16(af[i], bf[j],
                                                            acc[i][j], 0, 0, 0);
  }

#pragma unroll
  for (int i = 0; i < 4; i++) {
#pragma unroll
    for (int j = 0; j < 4; j++) {
      int c = bn + wn + j * 16 + l15;
#pragma unroll
      for (int r = 0; r < 4; r++) {
        int m = bm + wm + i * 16 + lq * 4 + r;
        out[(size_t)m * N + c] = f2bf(acc[i][j][r]);
      }
    }
  }
}

// -------------------------------------------------------------------------
// bf16 MFMA GEMM 128x64 tiles (512 blocks at N=512 -> 2 blocks/CU).
// EPI 1: f32 +bias token-major. EPI 2: f32 +bias +resid, NCHW store.
template <int EPI>
__global__ __launch_bounds__(256) void gemm_n64(
    const ushort* __restrict__ A, const ushort* __restrict__ Wm,
    const float* __restrict__ bias, float* __restrict__ out,
    const float* __restrict__ resid, int N, int K) {
  __shared__ alignas(16) ushort As[128 * 32];
  __shared__ alignas(16) ushort Bs[64 * 32];
  const int bn = blockIdx.x * 64, bm = blockIdx.y * 128;
  const int tid = threadIdx.x;
  const int w = tid >> 6, lane = tid & 63;
  const int wm = 64 * (w & 1), wn = 32 * (w >> 1);
  const int l15 = lane & 15, lq = lane >> 4;

  f32x4 acc[4][2];
#pragma unroll
  for (int i = 0; i < 4; i++)
#pragma unroll
    for (int j = 0; j < 2; j++) acc[i][j] = (f32x4){0.f, 0.f, 0.f, 0.f};

  const int srr = lane >> 2, sq1 = lane & 3;

  for (int k0 = 0; k0 < K; k0 += 32) {
    __syncthreads();
#pragma unroll
    for (int j = 0; j < 2; j++) {
      int r = 32 * w + 16 * j + srr;
      int q = (sq1 - (r >> 1)) & 3;
      GLD16(A + (size_t)(bm + r) * K + k0 + q * 8, &As[(32 * w + 16 * j) * 32]);
    }
    {
      int r = 16 * w + srr;
      int q = (sq1 - (r >> 1)) & 3;
      GLD16(Wm + (size_t)(bn + r) * K + k0 + q * 8, &Bs[(16 * w) * 32]);
    }
    __syncthreads();
    short8 af[4], bf[2];
#pragma unroll
    for (int nt = 0; nt < 4; nt++) {
      int r = wm + nt * 16 + l15;
      af[nt] = *(const short8*)&As[r * 32 + (((lq + (r >> 1)) & 3) * 8)];
    }
#pragma unroll
    for (int j = 0; j < 2; j++) {
      int c = wn + j * 16 + l15;
      bf[j] = *(const short8*)&Bs[c * 32 + (((lq + (c >> 1)) & 3) * 8)];
    }
#pragma unroll
    for (int i = 0; i < 4; i++)
#pragma unroll
      for (int j = 0; j < 2; j++)
        acc[i][j] = __builtin_amdgcn_mfma_f32_16x16x32_bf16(af[i], bf[j],
                                                            acc[i][j], 0, 0, 0);
  }

#pragma unroll
  for (int i = 0; i < 4; i++) {
#pragma unroll
    for (int j = 0; j < 2; j++) {
      int c = bn + wn + j * 16 + l15;
      float bv = bias[c];
#pragma unroll
      for (int r = 0; r < 4; r++) {
        int m = bm + wm + i * 16 + lq * 4 + r;
        float v = acc[i][j][r] + bv;
        if (EPI == 1) {
          out[(size_t)m * N + c] = v;
        } else {
          int b = m >> 10, s = m & (HW_ - 1);
          out[((size_t)(b * C_ + c)) * HW_ + s] = v + resid[(size_t)m * C_ + c];
        }
      }
    }
  }
}

// -------------------------------------------------------------------------
// K3a: token-axis L2 partial sums (512 blocks: bh x 8 token-segments)
__global__ __launch_bounds__(256) void qk_norms_stage1(
    const ushort* __restrict__ qkv, float* __restrict__ partials) {
  __shared__ float smq[32][65], smk[32][65];
  const int blk = blockIdx.x;
  const int bh = blk >> 3, seg = blk & 7;
  const int b = bh >> 3, h = bh & 7;
  const int tid = threadIdx.x;
  const int trow = tid >> 3, chunk = tid & 7;
  float sq[8] = {}, sk[8] = {};
  const ushort* base = qkv + (size_t)b * HW_ * C3_ + h * 64 + chunk * 8;
#pragma unroll
  for (int i = 0; i < 4; i++) {
    int n = seg * 128 + i * 32 + trow;
    const ushort* p = base + (size_t)n * C3_;
    ushort8 q8 = *(const ushort8*)p;
    ushort8 k8 = *(const ushort8*)(p + C_);
#pragma unroll
    for (int j = 0; j < 8; j++) {
      float qv = bf2f(q8[j]), kv = bf2f(k8[j]);
      sq[j] += qv * qv;
      sk[j] += kv * kv;
    }
  }
#pragma unroll
  for (int j = 0; j < 8; j++) {
    smq[trow][chunk * 8 + j] = sq[j];
    smk[trow][chunk * 8 + j] = sk[j];
  }
  __syncthreads();
  if (tid < 64) {
    float s = 0.f;
    for (int i = 0; i < 32; i++) s += smq[i][tid];
    partials[((size_t)(bh * 8 + seg) * 2 + 0) * 64 + tid] = s;
  } else if (tid < 128) {
    int d = tid - 64;
    float s = 0.f;
    for (int i = 0; i < 32; i++) s += smk[i][d];
    partials[((size_t)(bh * 8 + seg) * 2 + 1) * 64 + d] = s;
  }
}

// K3b: finalize norms
__global__ void qk_norms_stage2(const float* __restrict__ partials,
                                float* __restrict__ invq,
                                float* __restrict__ invk) {
  const int bh = blockIdx.x;
  const int tid = threadIdx.x;
  const int which = tid >> 6, d = tid & 63;
  float s = 0.f;
#pragma unroll
  for (int seg = 0; seg < 8; seg++)
    s += partials[((size_t)(bh * 8 + seg) * 2 + which) * 64 + d];
  float r = 1.0f / fmaxf(sqrtf(s), 1e-12f);
  if (which == 0) invq[bh * 64 + d] = r;
  else invk[bh * 64 + d] = r;
}

// -------------------------------------------------------------------------
// K4: MFMA flash attention. 8 waves = 128 queries/block; fixed-max softmax;
// K staged via global_load_lds with XOR chunk swizzle; V transposed with
// 2-way-free swizzled scalar writes; P via per-wave LDS round trip.
__global__ __launch_bounds__(512) void attn_mfma_kernel(
    const ushort* __restrict__ qkv, const float* __restrict__ invq,
    const float* __restrict__ invk, const float* __restrict__ temp,
    ushort* __restrict__ o) {
  __shared__ alignas(16) ushort Ks[64 * 64];    // [key][d], chunk-swizzled
  __shared__ alignas(16) ushort Vts[64][88];    // [d][key-swizzled]
  __shared__ alignas(16) ushort Ps[8][16][88];  // per-wave [row][key]

  const int tid = threadIdx.x;
  const int w = tid >> 6, lane = tid & 63;
  const int qgrp = lane >> 4, lcol = lane & 15;
  const int bh = blockIdx.x >> 3;
  const int qt = blockIdx.x & 7;
  const int b = bh >> 3, h = bh & 7;
  const int q0 = qt * 128;

  short8 qf[2];
  {
    const int m = q0 + w * 16 + lcol;
    const ushort* qrow = qkv + ((size_t)(b * HW_ + m)) * C3_ + h * 64;
    const float tmp = temp[h];
#pragma unroll
    for (int kc = 0; kc < 2; kc++) {
      union { short8 v; ushort u[8]; } pk;
#pragma unroll
      for (int j = 0; j < 8; j++) {
        int d = kc * 32 + qgrp * 8 + j;
        float s = invq[bh * 64 + d] * invk[bh * 64 + d] * tmp;
        pk.u[j] = f2bf(bf2f(qrow[d]) * s);
      }
      qf[kc] = pk.v;
    }
  }

  f32x4 of[4];
  float lsum[4] = {0.f, 0.f, 0.f, 0.f};
#pragma unroll
  for (int nt = 0; nt < 4; nt++) of[nt] = (f32x4){0.f, 0.f, 0.f, 0.f};

  const ushort* kg = qkv + (size_t)b * HW_ * C3_ + C_ + h * 64;

  // staging coords: 512 threads cover 64 rows x 8 chunks (of 8 bf16)
  const int srow = tid >> 3;
  const int sc = tid & 7;
  const int scg = sc ^ (srow & 7);  // global chunk fetched into physical slot sc
  const int vcol = (((srow >> 3) + sc) & 7) * 8 + (srow & 7);

  for (int kt = 0; kt < 16; kt++) {
    __syncthreads();
    // K: async direct-to-LDS, 16B per lane, wave-uniform base
    GLD16(kg + (size_t)(kt * 64 + srow) * C3_ + scg * 8, &Ks[w * 512]);
    {
      const ushort* vsrc = kg + C_ + (size_t)(kt * 64 + srow) * C3_ + sc * 8;
      ushort8 vv = *(const ushort8*)vsrc;
#pragma unroll
      for (int j = 0; j < 8; j++) Vts[sc * 8 + j][vcol] = vv[j];
    }
    __syncthreads();

    f32x4 sfr[4];
#pragma unroll
    for (int nt = 0; nt < 4; nt++) sfr[nt] = (f32x4){0.f, 0.f, 0.f, 0.f};
#pragma unroll
    for (int kc = 0; kc < 2; kc++) {
#pragma unroll
      for (int nt = 0; nt < 4; nt++) {
        int row = nt * 16 + lcol;
        short8 kf = *(const short8*)
            &Ks[row * 64 + (((kc * 4 + qgrp) ^ (row & 7)) * 8)];
        sfr[nt] =
            __builtin_amdgcn_mfma_f32_16x16x32_bf16(qf[kc], kf, sfr[nt], 0, 0, 0);
      }
    }

    // fixed-max softmax: e = exp(s); defer cross-lane sum to epilogue
#pragma unroll
    for (int nt = 0; nt < 4; nt++) {
#pragma unroll
      for (int r = 0; r < 4; r++) {
        float e = __expf(sfr[nt][r]);
        lsum[r] += e;
        Ps[w][qgrp * 4 + r][nt * 16 + lcol] = f2bf(e);
      }
    }

#pragma unroll
    for (int kc = 0; kc < 2; kc++) {
      short8 pf = *(const short8*)&Ps[w][lcol][kc * 32 + qgrp * 8];
#pragma unroll
      for (int nt = 0; nt < 4; nt++) {
        int d = nt * 16 + lcol;
        int cph = ((kc * 4 + qgrp) + (d >> 3)) & 7;
        short8 vf = *(const short8*)&Vts[d][cph * 8];
        of[nt] =
            __builtin_amdgcn_mfma_f32_16x16x32_bf16(pf, vf, of[nt], 0, 0, 0);
      }
    }
  }

  float inv[4];
#pragma unroll
  for (int r = 0; r < 4; r++) {
    float s = lsum[r];
    s += __shfl_xor(s, 1);
    s += __shfl_xor(s, 2);
    s += __shfl_xor(s, 4);
    s += __shfl_xor(s, 8);
    inv[r] = 1.0f / s;
  }
#pragma unroll
  for (int nt = 0; nt < 4; nt++) {
#pragma unroll
    for (int r = 0; r < 4; r++) {
      int m = q0 + w * 16 + qgrp * 4 + r;
      o[((size_t)(b * HW_ + m)) * C_ + h * 64 + nt * 16 + lcol] =
          f2bf(of[nt][r] * inv[r]);
    }
  }
}

// -------------------------------------------------------------------------
// K6: LayerNorm + residual(xT bf16). po -> f32 y in place; also writes bf16
// y into ybf (may alias xT: each thread reads its elements before writing).
__global__ void ln_residual_kernel(float* __restrict__ po, const ushort* xT,
                                   const float* __restrict__ g,
                                   const float* __restrict__ bb, ushort* ybf) {
  int token = blockIdx.x;
  int t = threadIdx.x;
  float* row = po + (size_t)token * C_;
  float v0 = row[t], v1 = row[t + 256];
  float s = v0 + v1;
#pragma unroll
  for (int off = 32; off; off >>= 1) s += __shfl_xor(s, off);
  __shared__ float wr[4];
  if ((t & 63) == 0) wr[t >> 6] = s;
  __syncthreads();
  float mu = (wr[0] + wr[1] + wr[2] + wr[3]) * (1.0f / C_);
  float d0 = v0 - mu, d1 = v1 - mu;
  float vs = d0 * d0 + d1 * d1;
#pragma unroll
  for (int off = 32; off; off >>= 1) vs += __shfl_xor(vs, off);
  __syncthreads();
  if ((t & 63) == 0) wr[t >> 6] = vs;
  __syncthreads();
  float var = (wr[0] + wr[1] + wr[2] + wr[3]) * (1.0f / C_);
  float rstd = rsqrtf(var + 1e-5f);
  float r0 = bf2f(xT[(size_t)token * C_ + t]);
  float r1 = bf2f(xT[(size_t)token * C_ + t + 256]);
  float o0 = d0 * rstd * g[t] + bb[t] + r0;
  float o1 = d1 * rstd * g[t + 256] + bb[t + 256] + r1;
  row[t] = o0;
  row[t + 256] = o1;
  ybf[(size_t)token * C_ + t] = f2bf(o0);
  ybf[(size_t)token * C_ + t + 256] = f2bf(o1);
}

// -------------------------------------------------------------------------
// K7: depthwise 3x3 SAME on bf16 y (token-major) -> bf16 out (+dw bias)
__global__ __launch_bounds__(256) void dwconv_kernel(
    const ushort* __restrict__ y, const float* __restrict__ w,
    const float* __restrict__ bias, ushort* __restrict__ out) {
  const int cg = threadIdx.x & 63, tg = threadIdx.x >> 6;
  const int c0 = cg * 8;
  float wreg[9][8], breg[8];
#pragma unroll
  for (int j = 0; j < 8; j++) {
    breg[j] = bias[c0 + j];
#pragma unroll
    for (int kk = 0; kk < 9; kk++) wreg[kk][j] = w[(c0 + j) * 9 + kk];
  }
  for (int i = 0; i < 4; i++) {
    int token = blockIdx.x * 16 + tg * 4 + i;
    int b = token >> 10, s = token & (HW_ - 1);
    int hh = s >> 5, ww = s & 31;
    float acc[8];
#pragma unroll
    for (int j = 0; j < 8; j++) acc[j] = breg[j];
#pragma unroll
    for (int ky = 0; ky < 3; ky++) {
      int yy = hh + ky - 1;
      if (yy < 0 || yy >= HH_) continue;
#pragma unroll
      for (int kx = 0; kx < 3; kx++) {
        int xx = ww + kx - 1;
        if (xx < 0 || xx >= WW_) continue;
        ushort8 v8 = *(const ushort8*)
            &y[((size_t)(b * HW_ + yy * 32 + xx)) * C_ + c0];
        const float* wk = wreg[ky * 3 + kx];
#pragma unroll
        for (int j = 0; j < 8; j++) acc[j] += wk[j] * bf2f(v8[j]);
      }
    }
    ushort8 pk;
#pragma unroll
    for (int j = 0; j < 8; j++) pk[j] = f2bf(acc[j]);
    *(ushort8*)&out[(size_t)token * C_ + c0] = pk;
  }
}

// -------------------------------------------------------------------------
extern "C" void kernel_launch(void* const* d_in, const int* in_sizes, int n_in,
                              void* d_out, int out_size, void* d_ws,
                              size_t ws_size, hipStream_t stream) {
  const float* x = (const float*)d_in[0];
  const float* qkv_w = (const float*)d_in[1];
  const float* proj_w = (const float*)d_in[2];
  const float* proj_b = (const float*)d_in[3];
  const float* temperature = (const float*)d_in[4];
  const float* ln_g = (const float*)d_in[5];
  const float* ln_b = (const float*)d_in[6];
  const float* pos = (const float*)d_in[7];
  const float* dw_w = (const float*)d_in[8];
  const float* dw_b = (const float*)d_in[9];
  const float* pw_w = (const float*)d_in[10];
  const float* pw_b = (const float*)d_in[11];
  float* out = (float*)d_out;

  float* ws = (float*)d_ws;
  // [0,24MB)    qkv_bf (bf16, exactly 24MB)
  // [24,32MB)   t_bf -> attn_out_bf -> dw_out_bf (bf16)
  // [32,48MB)   proj_out f32 -> y f32 (LN in-place, pw residual)
  // [48,56MB)   xT bf16 -> y_bf (ln overwrites in place)
  // [56,58.6MB) weights bf16
  // [60MB,...)  invq/invk/partials
  ushort* qkv_bf = (ushort*)ws;
  ushort* t_bf = (ushort*)(ws + (size_t)6 * 1024 * 1024);
  float* proj_out = ws + (size_t)8 * 1024 * 1024;
  ushort* xT_bf = (ushort*)(ws + (size_t)12 * 1024 * 1024);
  ushort* wts = (ushort*)(ws + (size_t)14 * 1024 * 1024);
  ushort* qkvw_bf = wts;
  ushort* projw_bf = wts + 786432;
  ushort* pww_bf = wts + 1048576;
  float* invq = ws + (size_t)15 * 1024 * 1024;
  float* invk = invq + 512;
  float* partials = invk + 512;  // 512*128 floats = 256 KB

  const int M = BB_ * HW_;  // 8192 tokens

  // 0) weights -> bf16
  cvt_weights_kernel<<<1310720 / 256, 256, 0, stream>>>(qkv_w, proj_w, pw_w,
                                                        wts);
  // 1) t = bf16(x^T + pos), xT = bf16(x^T)
  add_pos_kernel<<<dim3(16, 8, 8), 256, 0, stream>>>(x, pos, t_bf, xT_bf);
  // 2) qkv GEMM (bf16 out)
  gemm_128<<<dim3(C3_ / 128, M / 128), 256, 0, stream>>>(t_bf, qkvw_bf,
                                                         qkv_bf, C3_, C_);
  // 3) q/k token-axis norms (two-stage)
  qk_norms_stage1<<<512, 256, 0, stream>>>(qkv_bf, partials);
  qk_norms_stage2<<<64, 128, 0, stream>>>(partials, invq, invk);
  // 4) flash attention -> attn_out (bf16, reuses t region)
  attn_mfma_kernel<<<BB_ * NH_ * (HW_ / 128), 512, 0, stream>>>(
      qkv_bf, invq, invk, temperature, t_bf);
  // 5) proj GEMM (+bias, f32 out)
  gemm_n64<1><<<dim3(C_ / 64, M / 128), 256, 0, stream>>>(
      t_bf, projw_bf, proj_b, proj_out, nullptr, C_, C_);
  // 6) LayerNorm + residual(xT): proj_out -> y f32 (in place) + y_bf
  ln_residual_kernel<<<M, 256, 0, stream>>>(proj_out, xT_bf, ln_g, ln_b,
                                            xT_bf);
  // 7) depthwise 3x3 on bf16 y -> dw_out (bf16, reuses t region)
  dwconv_kernel<<<M / 16, 256, 0, stream>>>(xT_bf, dw_w, dw_b, t_bf);
  // 8) pointwise GEMM + pw_b + residual(y f32), NCHW -> out
  gemm_n64<2><<<dim3(C_ / 64, M / 128), 256, 0, stream>>>(
      t_bf, pww_bf, pw_b, out, proj_out, C_, C_);
}